// Round 1
// baseline (389.682 us; speedup 1.0000x reference)
//
#include <hip/hip_runtime.h>

#define MROWS 400000
#define NOBS 1024

// ---------------------------------------------------------------------------
// Fused single-pass kernel: one block (256 thr = 4 waves) per obstacle
// segment (segments are contiguous since seg ids are sorted; bounds via
// binary search). Softmax max-subtraction cancels algebraically in
// prob = e/sum(e); scores are O(1) so raw __expf is safe (verified in
// earlier rounds, absmax 4.9e-4).
//
// Per 64-row tile:
//   stage : 12 coalesced float4 loads/thread (ht,info,fut) -> LDS, row
//           stride 68 floats (17 float4). Row-wise b128 reads then map to
//           bank-group (lane+k4)%8 = 8 lanes/group (optimal), column-wise
//           reads map to (4r+lane)%32 = 2 lanes/bank (free).
//   MLP   : wave p computes h[4p..4p+4) for row=lane; w1/b1/w2 accesses are
//           wave-uniform (readfirstlane-forced) -> scalar loads, 0 VALU cost.
//   reduce: spart[4][64] -> score -> e_tile[row] = exp(score) (0 past rem).
//   accum : waves 0..2 own ht/info/fut, lane owns one dim:
//           acc += e[r]*T[r][lane]; wave 3 accumulates sum(e).
// Register double-buffer: tile t+1's global loads issue before tile t's
// MLP+accum so HBM latency hides under compute. Single LDS buffer
// (3*64*68*4 = 52 KB) -> 2 blocks/CU resident.
// ---------------------------------------------------------------------------
__global__ __launch_bounds__(256, 2) void fused_kernel(
    const float* __restrict__ ht, const float* __restrict__ info,
    const float* __restrict__ fut, const int* __restrict__ seg,
    const float* __restrict__ w1, const float* __restrict__ b1,
    const float* __restrict__ w2, const float* __restrict__ b2,
    float* __restrict__ out) {
    const int s = blockIdx.x;

    // segment bounds (seg sorted ascending)
    int lo = 0, hi = MROWS;
    while (lo < hi) { int mid = (lo + hi) >> 1; if (seg[mid] < s) lo = mid + 1; else hi = mid; }
    const int start = lo;
    hi = MROWS;
    while (lo < hi) { int mid = (lo + hi) >> 1; if (seg[mid] < s + 1) lo = mid + 1; else hi = mid; }
    const int end = lo;

    const int t    = threadIdx.x;
    const int lane = t & 63;
    const int p    = t >> 6;            // wave id 0..3

    __shared__ float Al[64 * 68];
    __shared__ float Bl[64 * 68];
    __shared__ float Fl[64 * 68];
    __shared__ float spart[4][64];
    __shared__ float e_tile[64];
    __shared__ float esum_sh;

    if (start >= end) {                 // shouldn't happen (M >> N), but safe
        if (p < 3) out[(size_t)s * 192 + p * 64 + lane] = 0.f;
        return;
    }

    const int ntiles = (end - start + 63) >> 6;

    // wave-uniform weight slice: this wave owns h[4p..4p+4)
    const int ps = __builtin_amdgcn_readfirstlane(p);
    const float* w1p = w1 + 4 * ps;     // w1p[k*16 + jj] = w1[k][4p+jj]
    float wb1[4], wb2[4];
#pragma unroll
    for (int j = 0; j < 4; ++j) { wb1[j] = b1[4 * ps + j]; wb2[j] = w2[4 * ps + j]; }
    const float bb2 = b2[0];

    float acc  = 0.f;                   // waves 0..2: weighted sum for dim=lane
    float esum = 0.f;                   // wave 3: running sum(e)

    float4 ra[4], rb[4], rf[4];         // register staging (double buffer)

    auto LOAD = [&](int tl) {
        const int r0 = start + (tl << 6);
#pragma unroll
        for (int u = 0; u < 4; ++u) {
            const int idx = u * 256 + t;        // float4 index in 16KB tile
            const int row = idx >> 4;
            const int c4  = idx & 15;
            int rg = r0 + row;
            if (rg >= MROWS) rg = MROWS - 1;    // clamp: data unused (e=0)
            const size_t off = (size_t)rg * 64 + c4 * 4;
            ra[u] = *(const float4*)(ht   + off);
            rb[u] = *(const float4*)(info + off);
            rf[u] = *(const float4*)(fut  + off);
        }
    };

    LOAD(0);

    for (int tl = 0; tl < ntiles; ++tl) {
        const int r0 = start + (tl << 6);
        int rem = end - r0; if (rem > 64) rem = 64;

        __syncthreads();                // previous tile's LDS reads complete
#pragma unroll
        for (int u = 0; u < 4; ++u) {
            const int idx = u * 256 + t;
            const int row = idx >> 4;
            const int c4  = idx & 15;
            const int a = row * 68 + c4 * 4;
            *(float4*)(Al + a) = ra[u];
            *(float4*)(Bl + a) = rb[u];
            *(float4*)(Fl + a) = rf[u];
        }
        __syncthreads();

        if (tl + 1 < ntiles) LOAD(tl + 1);  // prefetch next tile (overlaps MLP)

        // ---- MLP for row = lane, hidden units 4p..4p+3 ----
        float h0 = wb1[0], h1 = wb1[1], h2 = wb1[2], h3 = wb1[3];
        {
            const float* arow = Al + lane * 68;
            const float* brow = Bl + lane * 68;
#pragma unroll
            for (int k4 = 0; k4 < 16; ++k4) {
                const float4 v = *(const float4*)(arow + 4 * k4);
                const float* wk = w1p + (4 * k4) * 16;
                h0 += v.x * wk[0] + v.y * wk[16] + v.z * wk[32] + v.w * wk[48];
                h1 += v.x * wk[1] + v.y * wk[17] + v.z * wk[33] + v.w * wk[49];
                h2 += v.x * wk[2] + v.y * wk[18] + v.z * wk[34] + v.w * wk[50];
                h3 += v.x * wk[3] + v.y * wk[19] + v.z * wk[35] + v.w * wk[51];
            }
#pragma unroll
            for (int k4 = 0; k4 < 16; ++k4) {
                const float4 v = *(const float4*)(brow + 4 * k4);
                const float* wk = w1p + (64 + 4 * k4) * 16;
                h0 += v.x * wk[0] + v.y * wk[16] + v.z * wk[32] + v.w * wk[48];
                h1 += v.x * wk[1] + v.y * wk[17] + v.z * wk[33] + v.w * wk[49];
                h2 += v.x * wk[2] + v.y * wk[18] + v.z * wk[34] + v.w * wk[50];
                h3 += v.x * wk[3] + v.y * wk[19] + v.z * wk[35] + v.w * wk[51];
            }
        }
        float sp = fmaxf(h0, 0.f) * wb2[0] + fmaxf(h1, 0.f) * wb2[1]
                 + fmaxf(h2, 0.f) * wb2[2] + fmaxf(h3, 0.f) * wb2[3];
        spart[p][lane] = sp;
        __syncthreads();

        if (p == 0) {
            float sc = spart[0][lane] + spart[1][lane]
                     + spart[2][lane] + spart[3][lane] + bb2;
            e_tile[lane] = (lane < rem) ? __expf(sc) : 0.f;
        }
        __syncthreads();

        // ---- weighted accumulation ----
        if (p < 3) {
            const float* T = (p == 0) ? Al : (p == 1) ? Bl : Fl;
            const float* Tl = T + lane;
            int r = 0;
            for (; r + 4 <= rem; r += 4) {
                const float e0 = e_tile[r + 0];
                const float e1 = e_tile[r + 1];
                const float e2 = e_tile[r + 2];
                const float e3 = e_tile[r + 3];
                acc += e0 * Tl[(r + 0) * 68] + e1 * Tl[(r + 1) * 68]
                     + e2 * Tl[(r + 2) * 68] + e3 * Tl[(r + 3) * 68];
            }
            for (; r < rem; ++r) acc += e_tile[r] * Tl[r * 68];
        } else {
            esum += e_tile[lane];       // zeros past rem already handled
        }
    }

    // ---- finalize ----
    if (p == 3) {
        float v = esum;
#pragma unroll
        for (int off = 32; off > 0; off >>= 1) v += __shfl_xor(v, off, 64);
        if (lane == 0) esum_sh = v;
    }
    __syncthreads();
    if (p < 3) out[(size_t)s * 192 + p * 64 + lane] = acc / esum_sh;
}

extern "C" void kernel_launch(void* const* d_in, const int* in_sizes, int n_in,
                              void* d_out, int out_size, void* d_ws, size_t ws_size,
                              hipStream_t stream) {
    const float* ht   = (const float*)d_in[0];
    const float* info = (const float*)d_in[1];
    const float* fut  = (const float*)d_in[2];
    const int*   seg  = (const int*)d_in[3];
    const float* w1   = (const float*)d_in[4];
    const float* b1   = (const float*)d_in[5];
    const float* w2   = (const float*)d_in[6];
    const float* b2   = (const float*)d_in[7];

    float* out = (float*)d_out;
    (void)d_ws; (void)ws_size;

    fused_kernel<<<NOBS, 256, 0, stream>>>(ht, info, fut, seg, w1, b1, w2, b2, out);
}

// Round 3
// 358.547 us; speedup vs baseline: 1.0868x; 1.0868x over previous
//
#include <hip/hip_runtime.h>

#define MROWS 400000
#define NOBS 1024

// ---------------------------------------------------------------------------
// Fused single-pass kernel: one block (256 thr = 4 waves) per obstacle
// segment (contiguous since seg ids are sorted; bounds via binary search).
// Softmax max-subtraction cancels algebraically in prob = e/sum(e); scores
// are O(1) so raw __expf is safe (verified, absmax 4.9e-4).
//
// R2/R3 fix: R1's register double-buffer used float4 ra[4]/rb[4]/rf[4]
// captured by-reference in a LOAD lambda -> compiler demoted the arrays to
// SCRATCH (VGPR_Count=68; WRITE_SIZE showed 307 MB of scratch writes =
// 192 B/thread/tile, exactly the staging size). Fix = individually NAMED
// float4 registers + explicit macros; nothing runtime-indexed, nothing
// captured. (R2 submission hit an infra failure; this is the same kernel.)
//
// LDS row stride 68 floats (17 float4): row-wise b128 MLP reads hit bank
// group (17*row + k4) % 8 -> 8 lanes/group = b128 minimum (conflict-free);
// column-wise accum reads are 64 consecutive floats = 2 lanes/bank (free).
// w1/b1/w2 reads are wave-uniform (readfirstlane-forced) -> s_load.
// LDS = 52.5 KB -> 3 blocks/CU (157.7 KB of 160 KiB).
// ---------------------------------------------------------------------------
__global__ __launch_bounds__(256, 3) void fused_kernel(
    const float* __restrict__ ht, const float* __restrict__ info,
    const float* __restrict__ fut, const int* __restrict__ seg,
    const float* __restrict__ w1, const float* __restrict__ b1,
    const float* __restrict__ w2, const float* __restrict__ b2,
    float* __restrict__ out) {
    const int s = blockIdx.x;

    // segment bounds (seg sorted ascending)
    int lo = 0, hi = MROWS;
    while (lo < hi) { int mid = (lo + hi) >> 1; if (seg[mid] < s) lo = mid + 1; else hi = mid; }
    const int start = lo;
    hi = MROWS;
    while (lo < hi) { int mid = (lo + hi) >> 1; if (seg[mid] < s + 1) lo = mid + 1; else hi = mid; }
    const int end = lo;

    const int t    = threadIdx.x;
    const int lane = t & 63;
    const int p    = t >> 6;            // wave id 0..3

    __shared__ float Al[64 * 68];
    __shared__ float Bl[64 * 68];
    __shared__ float Fl[64 * 68];
    __shared__ float spart[4][64];
    __shared__ float e_tile[64];
    __shared__ float esum_sh;

    if (start >= end) {                 // shouldn't happen (M >> N), but safe
        if (p < 3) out[(size_t)s * 192 + p * 64 + lane] = 0.f;
        return;
    }

    const int ntiles = (end - start + 63) >> 6;

    // wave-uniform weight slice: this wave owns h[4p..4p+4)
    const int ps = __builtin_amdgcn_readfirstlane(p);
    const float* w1p = w1 + 4 * ps;     // w1p[k*16 + jj] = w1[k][4p+jj]
    const float wb10 = b1[4 * ps + 0], wb11 = b1[4 * ps + 1];
    const float wb12 = b1[4 * ps + 2], wb13 = b1[4 * ps + 3];
    const float wv20 = w2[4 * ps + 0], wv21 = w2[4 * ps + 1];
    const float wv22 = w2[4 * ps + 2], wv23 = w2[4 * ps + 3];
    const float bb2 = b2[0];

    float acc  = 0.f;                   // waves 0..2: weighted sum for dim=lane
    float esum = 0.f;                   // wave 3: running sum(e)

    // staging layout: thread t loads rows {r_t, r_t+16, r_t+32, r_t+48} of
    // the 64-row tile, float4 column c4o/4. All loads coalesced (16 thr span
    // one 256 B row).
    const int r_t  = t >> 4;            // 0..15
    const int c4o  = (t & 15) * 4;      // float offset within row
    const int lbase = r_t * 68 + c4o;   // LDS float offset for u=0

    // NAMED register staging (double buffer) — never indexed, never captured.
    float4 ra0, ra1, ra2, ra3, rb0, rb1, rb2, rb3, rf0, rf1, rf2, rf3;

#define GLOAD(tl_) {                                                          \
    const int rr = start + ((tl_) << 6) + r_t;                                \
    int r0c = rr;      if (r0c >= MROWS) r0c = MROWS - 1;                     \
    int r1c = rr + 16; if (r1c >= MROWS) r1c = MROWS - 1;                     \
    int r2c = rr + 32; if (r2c >= MROWS) r2c = MROWS - 1;                     \
    int r3c = rr + 48; if (r3c >= MROWS) r3c = MROWS - 1;                     \
    const size_t o0 = (size_t)r0c * 64 + c4o;                                 \
    const size_t o1 = (size_t)r1c * 64 + c4o;                                 \
    const size_t o2 = (size_t)r2c * 64 + c4o;                                 \
    const size_t o3 = (size_t)r3c * 64 + c4o;                                 \
    ra0 = *(const float4*)(ht + o0);   ra1 = *(const float4*)(ht + o1);       \
    ra2 = *(const float4*)(ht + o2);   ra3 = *(const float4*)(ht + o3);       \
    rb0 = *(const float4*)(info + o0); rb1 = *(const float4*)(info + o1);     \
    rb2 = *(const float4*)(info + o2); rb3 = *(const float4*)(info + o3);     \
    rf0 = *(const float4*)(fut + o0);  rf1 = *(const float4*)(fut + o1);      \
    rf2 = *(const float4*)(fut + o2);  rf3 = *(const float4*)(fut + o3); }

#define LSTORE() {                                                            \
    *(float4*)(Al + lbase)        = ra0; *(float4*)(Al + lbase + 1088) = ra1; \
    *(float4*)(Al + lbase + 2176) = ra2; *(float4*)(Al + lbase + 3264) = ra3; \
    *(float4*)(Bl + lbase)        = rb0; *(float4*)(Bl + lbase + 1088) = rb1; \
    *(float4*)(Bl + lbase + 2176) = rb2; *(float4*)(Bl + lbase + 3264) = rb3; \
    *(float4*)(Fl + lbase)        = rf0; *(float4*)(Fl + lbase + 1088) = rf1; \
    *(float4*)(Fl + lbase + 2176) = rf2; *(float4*)(Fl + lbase + 3264) = rf3; }

    GLOAD(0);

    for (int tl = 0; tl < ntiles; ++tl) {
        const int r0 = start + (tl << 6);
        int rem = end - r0; if (rem > 64) rem = 64;

        __syncthreads();                // previous tile's LDS reads complete
        LSTORE();
        __syncthreads();

        if (tl + 1 < ntiles) GLOAD(tl + 1);  // prefetch overlaps MLP+accum

        // ---- MLP for row = lane, hidden units 4p..4p+3 ----
        float h0 = wb10, h1 = wb11, h2 = wb12, h3 = wb13;
        {
            const float* arow = Al + lane * 68;
            const float* brow = Bl + lane * 68;
#pragma unroll
            for (int k4 = 0; k4 < 16; ++k4) {
                const float4 v = *(const float4*)(arow + 4 * k4);
                const float* wk = w1p + (4 * k4) * 16;
                h0 += v.x * wk[0] + v.y * wk[16] + v.z * wk[32] + v.w * wk[48];
                h1 += v.x * wk[1] + v.y * wk[17] + v.z * wk[33] + v.w * wk[49];
                h2 += v.x * wk[2] + v.y * wk[18] + v.z * wk[34] + v.w * wk[50];
                h3 += v.x * wk[3] + v.y * wk[19] + v.z * wk[35] + v.w * wk[51];
            }
#pragma unroll
            for (int k4 = 0; k4 < 16; ++k4) {
                const float4 v = *(const float4*)(brow + 4 * k4);
                const float* wk = w1p + (64 + 4 * k4) * 16;
                h0 += v.x * wk[0] + v.y * wk[16] + v.z * wk[32] + v.w * wk[48];
                h1 += v.x * wk[1] + v.y * wk[17] + v.z * wk[33] + v.w * wk[49];
                h2 += v.x * wk[2] + v.y * wk[18] + v.z * wk[34] + v.w * wk[50];
                h3 += v.x * wk[3] + v.y * wk[19] + v.z * wk[35] + v.w * wk[51];
            }
        }
        float sp = fmaxf(h0, 0.f) * wv20 + fmaxf(h1, 0.f) * wv21
                 + fmaxf(h2, 0.f) * wv22 + fmaxf(h3, 0.f) * wv23;
        spart[p][lane] = sp;
        __syncthreads();

        if (p == 0) {
            float sc = spart[0][lane] + spart[1][lane]
                     + spart[2][lane] + spart[3][lane] + bb2;
            e_tile[lane] = (lane < rem) ? __expf(sc) : 0.f;
        }
        __syncthreads();

        // ---- weighted accumulation ----
        if (p < 3) {
            const float* T = (p == 0) ? Al : (p == 1) ? Bl : Fl;
            const float* Tl = T + lane;
            int r = 0;
            for (; r + 4 <= rem; r += 4) {
                const float e0 = e_tile[r + 0];
                const float e1 = e_tile[r + 1];
                const float e2 = e_tile[r + 2];
                const float e3 = e_tile[r + 3];
                acc += e0 * Tl[(r + 0) * 68] + e1 * Tl[(r + 1) * 68]
                     + e2 * Tl[(r + 2) * 68] + e3 * Tl[(r + 3) * 68];
            }
            for (; r < rem; ++r) acc += e_tile[r] * Tl[r * 68];
        } else {
            esum += e_tile[lane];       // zeros past rem already handled
        }
    }

    // ---- finalize ----
    if (p == 3) {
        float v = esum;
#pragma unroll
        for (int off = 32; off > 0; off >>= 1) v += __shfl_xor(v, off, 64);
        if (lane == 0) esum_sh = v;
    }
    __syncthreads();
    if (p < 3) out[(size_t)s * 192 + p * 64 + lane] = acc / esum_sh;
}

extern "C" void kernel_launch(void* const* d_in, const int* in_sizes, int n_in,
                              void* d_out, int out_size, void* d_ws, size_t ws_size,
                              hipStream_t stream) {
    const float* ht   = (const float*)d_in[0];
    const float* info = (const float*)d_in[1];
    const float* fut  = (const float*)d_in[2];
    const int*   seg  = (const int*)d_in[3];
    const float* w1   = (const float*)d_in[4];
    const float* b1   = (const float*)d_in[5];
    const float* w2   = (const float*)d_in[6];
    const float* b2   = (const float*)d_in[7];

    float* out = (float*)d_out;
    (void)d_ws; (void)ws_size;

    fused_kernel<<<NOBS, 256, 0, stream>>>(ht, info, fut, seg, w1, b1, w2, b2, out);
}

// Round 4
// 357.874 us; speedup vs baseline: 1.0889x; 1.0019x over previous
//
#include <hip/hip_runtime.h>

#define MROWS 400000
#define NOBS 1024

// ---------------------------------------------------------------------------
// R4: latency-bound fix (R3: hbm 11%, VALU 32%, occ 26% -> everything idle).
//  * seg bounds precomputed once (bounds_kernel) -> no 2x19-step serial
//    binary-search pointer-chase per block.
//  * fut dropped from LDS (only used in accum; read coalesced from global,
//    still exactly once) -> LDS 53.8 -> 35.5 KB -> 4 blocks/CU resident.
//  * each segment SPLIT across 2 or 4 blocks (strided tiles); partial
//    weighted sums + esum land in workspace; tiny finalize kernel reduces.
//    Grid 2048/4096 -> 8-16 blocks/CU of work, 16 waves resident: per-tile
//    stalls overlap across blocks (TLP) instead of relying on a register
//    prefetch whose 48-VGPR liveness strangled the compiler (R3 VGPR=68).
//  * GLOAD issued immediately before LSTORE: staging regs live ~10 instrs.
// Datapath (verified R3, absmax 4.9e-4): MLP on LDS rows (stride 68 floats:
// b128 row reads 8 lanes/bank-group = conflict-free; column accum reads
// 2 lanes/bank = free), weights via wave-uniform s_load, softmax
// max-subtraction cancels algebraically, raw __expf.
// ---------------------------------------------------------------------------

__global__ void bounds_kernel(const int* __restrict__ seg, int* __restrict__ starts) {
    const int i = blockIdx.x * 256 + threadIdx.x;
    if (i >= MROWS) return;
    const int a = seg[i];
    if (i == 0) {
        for (int j = 0; j <= a; ++j) starts[j] = 0;
    } else {
        const int b = seg[i - 1];
        for (int j = b + 1; j <= a; ++j) starts[j] = i;   // usually 0-1 iters
    }
    if (i == MROWS - 1) {
        for (int j = a + 1; j <= NOBS; ++j) starts[j] = MROWS;
    }
}

template <int SPLIT>
__global__ __launch_bounds__(256, 4) void fused_kernel(
    const float* __restrict__ ht, const float* __restrict__ info,
    const float* __restrict__ fut, const int* __restrict__ starts,
    const float* __restrict__ w1, const float* __restrict__ b1,
    const float* __restrict__ w2, const float* __restrict__ b2,
    float* __restrict__ partials) {
    const int s = blockIdx.x / SPLIT;   // SPLIT is 2 or 4 -> shift
    const int q = blockIdx.x % SPLIT;

    const int start = starts[s];
    const int end   = starts[s + 1];

    const int t    = threadIdx.x;
    const int lane = t & 63;
    const int p    = t >> 6;            // wave id 0..3

    __shared__ float Al[64 * 68];
    __shared__ float Bl[64 * 68];
    __shared__ float spart[4][64];
    __shared__ float e_tile[64];
    __shared__ float fpart[64];
    __shared__ float esum_sh;

    const int ntiles = (end - start + 63) >> 6;

    // wave-uniform weight slice: this wave owns h[4p..4p+4)
    const int ps = __builtin_amdgcn_readfirstlane(p);
    const float* w1p = w1 + 4 * ps;     // w1p[k*16 + jj] = w1[k][4p+jj]
    const float wb10 = b1[4 * ps + 0], wb11 = b1[4 * ps + 1];
    const float wb12 = b1[4 * ps + 2], wb13 = b1[4 * ps + 3];
    const float wv20 = w2[4 * ps + 0], wv21 = w2[4 * ps + 1];
    const float wv22 = w2[4 * ps + 2], wv23 = w2[4 * ps + 3];
    const float bb2 = b2[0];

    // acc: wave0 = ht dim accum, wave1 = info, wave2/3 = fut rows halves
    float acc  = 0.f;
    float esum = 0.f;                   // wave 3 only

    // staging: thread t loads rows {r_t, r_t+16, r_t+32, r_t+48}, float4 col c4o/4
    const int r_t   = t >> 4;           // 0..15
    const int c4o   = (t & 15) * 4;     // float offset within row
    const int lbase = r_t * 68 + c4o;   // LDS float offset

    float4 ra0, ra1, ra2, ra3, rb0, rb1, rb2, rb3;   // named, short-lived

    for (int tl = q; tl < ntiles; tl += SPLIT) {
        const int r0 = start + (tl << 6);
        int rem = end - r0; if (rem > 64) rem = 64;

        __syncthreads();                // previous tile's LDS reads complete

        {   // GLOAD: issued right before use -> 32 VGPRs live briefly
            const int rr = r0 + r_t;
            int r0c = rr;      if (r0c >= MROWS) r0c = MROWS - 1;
            int r1c = rr + 16; if (r1c >= MROWS) r1c = MROWS - 1;
            int r2c = rr + 32; if (r2c >= MROWS) r2c = MROWS - 1;
            int r3c = rr + 48; if (r3c >= MROWS) r3c = MROWS - 1;
            const size_t o0 = (size_t)r0c * 64 + c4o;
            const size_t o1 = (size_t)r1c * 64 + c4o;
            const size_t o2 = (size_t)r2c * 64 + c4o;
            const size_t o3 = (size_t)r3c * 64 + c4o;
            ra0 = *(const float4*)(ht + o0);   ra1 = *(const float4*)(ht + o1);
            ra2 = *(const float4*)(ht + o2);   ra3 = *(const float4*)(ht + o3);
            rb0 = *(const float4*)(info + o0); rb1 = *(const float4*)(info + o1);
            rb2 = *(const float4*)(info + o2); rb3 = *(const float4*)(info + o3);
        }
        *(float4*)(Al + lbase)        = ra0; *(float4*)(Al + lbase + 1088) = ra1;
        *(float4*)(Al + lbase + 2176) = ra2; *(float4*)(Al + lbase + 3264) = ra3;
        *(float4*)(Bl + lbase)        = rb0; *(float4*)(Bl + lbase + 1088) = rb1;
        *(float4*)(Bl + lbase + 2176) = rb2; *(float4*)(Bl + lbase + 3264) = rb3;
        __syncthreads();

        // ---- MLP for row = lane, hidden units 4p..4p+3 ----
        float h0 = wb10, h1 = wb11, h2 = wb12, h3 = wb13;
        {
            const float* arow = Al + lane * 68;
            const float* brow = Bl + lane * 68;
#pragma unroll
            for (int k4 = 0; k4 < 16; ++k4) {
                const float4 v = *(const float4*)(arow + 4 * k4);
                const float* wk = w1p + (4 * k4) * 16;
                h0 += v.x * wk[0] + v.y * wk[16] + v.z * wk[32] + v.w * wk[48];
                h1 += v.x * wk[1] + v.y * wk[17] + v.z * wk[33] + v.w * wk[49];
                h2 += v.x * wk[2] + v.y * wk[18] + v.z * wk[34] + v.w * wk[50];
                h3 += v.x * wk[3] + v.y * wk[19] + v.z * wk[35] + v.w * wk[51];
            }
#pragma unroll
            for (int k4 = 0; k4 < 16; ++k4) {
                const float4 v = *(const float4*)(brow + 4 * k4);
                const float* wk = w1p + (64 + 4 * k4) * 16;
                h0 += v.x * wk[0] + v.y * wk[16] + v.z * wk[32] + v.w * wk[48];
                h1 += v.x * wk[1] + v.y * wk[17] + v.z * wk[33] + v.w * wk[49];
                h2 += v.x * wk[2] + v.y * wk[18] + v.z * wk[34] + v.w * wk[50];
                h3 += v.x * wk[3] + v.y * wk[19] + v.z * wk[35] + v.w * wk[51];
            }
        }
        const float sp = fmaxf(h0, 0.f) * wv20 + fmaxf(h1, 0.f) * wv21
                       + fmaxf(h2, 0.f) * wv22 + fmaxf(h3, 0.f) * wv23;
        spart[p][lane] = sp;
        __syncthreads();

        if (p == 0) {
            const float sc = spart[0][lane] + spart[1][lane]
                           + spart[2][lane] + spart[3][lane] + bb2;
            e_tile[lane] = (lane < rem) ? __expf(sc) : 0.f;
        }
        __syncthreads();

        // ---- weighted accumulation ----
        if (p < 2) {
            // LDS tiles always hold 64 valid finite rows (clamped dups);
            // e_tile is zero past rem -> loop full 64, no tail.
            const float* Tl = ((p == 0) ? Al : Bl) + lane;
#pragma unroll 4
            for (int r = 0; r < 64; ++r) acc += e_tile[r] * Tl[r * 68];
        } else {
            // fut straight from global, coalesced 256B per row-instr
            const int rlo = (p - 2) * 32;
            int rhi = rem - rlo; if (rhi > 32) rhi = 32; // rows this wave
            const float* fb = fut + (size_t)(r0 + rlo) * 64 + lane;
            int r = 0;
            for (; r + 4 <= rhi; r += 4) {
                const float e0 = e_tile[rlo + r + 0];
                const float e1 = e_tile[rlo + r + 1];
                const float e2 = e_tile[rlo + r + 2];
                const float e3 = e_tile[rlo + r + 3];
                const float f0 = fb[(size_t)(r + 0) * 64];
                const float f1 = fb[(size_t)(r + 1) * 64];
                const float f2 = fb[(size_t)(r + 2) * 64];
                const float f3 = fb[(size_t)(r + 3) * 64];
                acc += e0 * f0 + e1 * f1 + e2 * f2 + e3 * f3;
            }
            for (; r < rhi; ++r) acc += e_tile[rlo + r] * fb[(size_t)r * 64];
            if (p == 3) {
#pragma unroll 4
                for (int rr = 0; rr < 64; ++rr) esum += (lane == 0) ? e_tile[rr] : 0.f;
            }
        }
    }

    // ---- merge wave partials, write to workspace ----
    float* P = partials + (size_t)(s * SPLIT + q) * 193;
    if (p == 3) {
        fpart[lane] = acc;              // fut rows-32..63 partial
        if (lane == 0) esum_sh = esum;  // esum accumulated on lane 0 only
    }
    __syncthreads();
    if (p == 0)      P[lane]       = acc;
    else if (p == 1) P[64 + lane]  = acc;
    else if (p == 2) {
        P[128 + lane] = acc + fpart[lane];
        if (lane == 0) P[192] = esum_sh;
    }
}

template <int SPLIT>
__global__ void finalize_kernel(const float* __restrict__ partials,
                                float* __restrict__ out) {
    const int s = blockIdx.x;
    const int d = threadIdx.x;          // 0..191
    float num = 0.f, den = 0.f;
#pragma unroll
    for (int qq = 0; qq < SPLIT; ++qq) {
        const float* P = partials + (size_t)(s * SPLIT + qq) * 193;
        num += P[d];
        den += P[192];
    }
    out[(size_t)s * 192 + d] = num / den;
}

extern "C" void kernel_launch(void* const* d_in, const int* in_sizes, int n_in,
                              void* d_out, int out_size, void* d_ws, size_t ws_size,
                              hipStream_t stream) {
    const float* ht   = (const float*)d_in[0];
    const float* info = (const float*)d_in[1];
    const float* fut  = (const float*)d_in[2];
    const int*   seg  = (const int*)d_in[3];
    const float* w1   = (const float*)d_in[4];
    const float* b1   = (const float*)d_in[5];
    const float* w2   = (const float*)d_in[6];
    const float* b2   = (const float*)d_in[7];

    float* out = (float*)d_out;

    int*   starts   = (int*)d_ws;                  // 1025 ints
    float* partials = (float*)d_ws + 1056;         // 16B-aligned tail

    bounds_kernel<<<(MROWS + 255) / 256, 256, 0, stream>>>(seg, starts);

    const size_t need4 = 4224 + (size_t)NOBS * 4 * 193 * 4;
    if (ws_size >= need4) {
        fused_kernel<4><<<NOBS * 4, 256, 0, stream>>>(ht, info, fut, starts,
                                                      w1, b1, w2, b2, partials);
        finalize_kernel<4><<<NOBS, 192, 0, stream>>>(partials, out);
    } else {
        fused_kernel<2><<<NOBS * 2, 256, 0, stream>>>(ht, info, fut, starts,
                                                      w1, b1, w2, b2, partials);
        finalize_kernel<2><<<NOBS, 192, 0, stream>>>(partials, out);
    }
}

// Round 5
// 349.918 us; speedup vs baseline: 1.1136x; 1.0227x over previous
//
#include <hip/hip_runtime.h>

#define MROWS 400000
#define NOBS 1024
#define NTILES 6250   // MROWS / 64 exactly

// ---------------------------------------------------------------------------
// R5: DE-FUSE. Three rounds of the barrier-phased fused kernel all plateaued
// at 184-194 us regardless of occupancy (26->38%) or fut placement -> the
// phase structure is the tax. Empirics from R0: barrier-free streaming pool
// hit 4 TB/s; per-thread-row score hit only 2.1 TB/s (64 cache lines per
// wave instruction -> L1-miss/transaction bound).
// Plan: (A) score_kernel = LDS-tile staged MLP (coalesced loads, verified
// spart datapath) WITHOUT the accum/exp-coupled phases -> writes evec.
// (B) pool_kernel = R0's proven streaming structure + precomputed bounds +
// float4 lanes + 16 rows in flight + optional SPLIT=2 with finalize.
// ---------------------------------------------------------------------------

__global__ void bounds_kernel(const int* __restrict__ seg, int* __restrict__ starts) {
    const int i = blockIdx.x * 256 + threadIdx.x;
    if (i >= MROWS) return;
    const int a = seg[i];
    if (i == 0) {
        for (int j = 0; j <= a; ++j) starts[j] = 0;
    } else {
        const int b = seg[i - 1];
        for (int j = b + 1; j <= a; ++j) starts[j] = i;   // usually 0-1 iters
    }
    if (i == MROWS - 1) {
        for (int j = a + 1; j <= NOBS; ++j) starts[j] = MROWS;
    }
}

// ---- Kernel A: tile-staged scoring MLP -> evec[row] = exp(score) ---------
// Grid-stride over 6250 tiles of 64 rows (exact). Per tile: coalesced float4
// stage of ht+info into LDS (stride 68 -> conflict-free b128 row reads),
// wave p computes h[4p..4p+3] for row=lane (weights wave-uniform s_loads),
// spart reduce, wave0 exp+write. 3 barriers/tile, no global-latency chains.
__global__ __launch_bounds__(256, 4) void score_kernel(
    const float* __restrict__ ht, const float* __restrict__ info,
    const float* __restrict__ w1, const float* __restrict__ b1,
    const float* __restrict__ w2, const float* __restrict__ b2,
    float* __restrict__ evec) {
    const int t    = threadIdx.x;
    const int lane = t & 63;
    const int p    = t >> 6;

    __shared__ float Al[64 * 68];
    __shared__ float Bl[64 * 68];
    __shared__ float spart[4][64];

    const int ps = __builtin_amdgcn_readfirstlane(p);
    const float* w1p = w1 + 4 * ps;
    const float wb10 = b1[4 * ps + 0], wb11 = b1[4 * ps + 1];
    const float wb12 = b1[4 * ps + 2], wb13 = b1[4 * ps + 3];
    const float wv20 = w2[4 * ps + 0], wv21 = w2[4 * ps + 1];
    const float wv22 = w2[4 * ps + 2], wv23 = w2[4 * ps + 3];
    const float bb2 = b2[0];

    const int r_t   = t >> 4;            // 0..15
    const int c4o   = (t & 15) * 4;      // float offset within 64-float row
    const int lbase = r_t * 68 + c4o;

    float4 ra0, ra1, ra2, ra3, rb0, rb1, rb2, rb3;  // named, short-lived

    for (int tile = blockIdx.x; tile < NTILES; tile += gridDim.x) {
        const size_t rbase = (size_t)tile * 64;

        __syncthreads();                 // LDS reuse guard (prev tile done)
        {
            const size_t o0 = (rbase + r_t) * 64 + c4o;   // rows r_t,+16,+32,+48
            ra0 = *(const float4*)(ht + o0);
            ra1 = *(const float4*)(ht + o0 + 1024);
            ra2 = *(const float4*)(ht + o0 + 2048);
            ra3 = *(const float4*)(ht + o0 + 3072);
            rb0 = *(const float4*)(info + o0);
            rb1 = *(const float4*)(info + o0 + 1024);
            rb2 = *(const float4*)(info + o0 + 2048);
            rb3 = *(const float4*)(info + o0 + 3072);
        }
        *(float4*)(Al + lbase)        = ra0; *(float4*)(Al + lbase + 1088) = ra1;
        *(float4*)(Al + lbase + 2176) = ra2; *(float4*)(Al + lbase + 3264) = ra3;
        *(float4*)(Bl + lbase)        = rb0; *(float4*)(Bl + lbase + 1088) = rb1;
        *(float4*)(Bl + lbase + 2176) = rb2; *(float4*)(Bl + lbase + 3264) = rb3;
        __syncthreads();

        float h0 = wb10, h1 = wb11, h2 = wb12, h3 = wb13;
        {
            const float* arow = Al + lane * 68;
            const float* brow = Bl + lane * 68;
#pragma unroll
            for (int k4 = 0; k4 < 16; ++k4) {
                const float4 v = *(const float4*)(arow + 4 * k4);
                const float* wk = w1p + (4 * k4) * 16;
                h0 += v.x * wk[0] + v.y * wk[16] + v.z * wk[32] + v.w * wk[48];
                h1 += v.x * wk[1] + v.y * wk[17] + v.z * wk[33] + v.w * wk[49];
                h2 += v.x * wk[2] + v.y * wk[18] + v.z * wk[34] + v.w * wk[50];
                h3 += v.x * wk[3] + v.y * wk[19] + v.z * wk[35] + v.w * wk[51];
            }
#pragma unroll
            for (int k4 = 0; k4 < 16; ++k4) {
                const float4 v = *(const float4*)(brow + 4 * k4);
                const float* wk = w1p + (64 + 4 * k4) * 16;
                h0 += v.x * wk[0] + v.y * wk[16] + v.z * wk[32] + v.w * wk[48];
                h1 += v.x * wk[1] + v.y * wk[17] + v.z * wk[33] + v.w * wk[49];
                h2 += v.x * wk[2] + v.y * wk[18] + v.z * wk[34] + v.w * wk[50];
                h3 += v.x * wk[3] + v.y * wk[19] + v.z * wk[35] + v.w * wk[51];
            }
        }
        const float sp = fmaxf(h0, 0.f) * wv20 + fmaxf(h1, 0.f) * wv21
                       + fmaxf(h2, 0.f) * wv22 + fmaxf(h3, 0.f) * wv23;
        spart[p][lane] = sp;
        __syncthreads();

        if (p == 0) {
            const float sc = spart[0][lane] + spart[1][lane]
                           + spart[2][lane] + spart[3][lane] + bb2;
            evec[rbase + lane] = __expf(sc);   // coalesced 256B per tile
        }
    }
}

// ---- Kernel B: streaming weighted pool (R0 structure, upgraded) ----------
// 6 waves = 3 arrays x 2 row-teams. Lane: ro=lane>>4 (row of 4), c4=(lane&15)*4
// -> one instr covers 4 rows x 256B, fully coalesced. 16 rows in flight.
// Fold ro-groups via shfl_xor(16|32); fold teams via LDS. No barriers in loop.
template <int SPLIT>
__global__ __launch_bounds__(384) void pool_kernel(
    const float* __restrict__ ht, const float* __restrict__ info,
    const float* __restrict__ fut, const int* __restrict__ starts,
    const float* __restrict__ evec, float* __restrict__ dst) {
    const int s = blockIdx.x / SPLIT;
    const int q = blockIdx.x % SPLIT;
    const int start = starts[s];
    const int end   = starts[s + 1];

    const int len   = end - start;
    const int chunk = (len + SPLIT - 1) / SPLIT;
    int rbeg0 = start + q * chunk;
    int rend0 = rbeg0 + chunk;
    if (rbeg0 > end) rbeg0 = end;
    if (rend0 > end) rend0 = end;

    const int t    = threadIdx.x;
    const int wave = t >> 6;           // 0..5
    const int lane = t & 63;
    const int arr  = wave >> 1;        // 0,1,2 -> ht, info, fut
    const int team = wave & 1;
    const float* base = (arr == 0) ? ht : (arr == 1) ? info : fut;
    const int ro = lane >> 4;          // 0..3
    const int c4 = (lane & 15) * 4;

    const int midr = (rbeg0 + rend0) >> 1;
    const int rbeg = team ? midr : rbeg0;
    const int rend = team ? rend0 : midr;

    float ax = 0.f, ay = 0.f, az = 0.f, aw = 0.f, ds = 0.f;
    int r = rbeg;
    for (; r + 16 <= rend; r += 16) {     // 16 rows: 4 x-loads + 4 e-loads in flight
        const float4 x0 = *(const float4*)(base + (size_t)(r +  0 + ro) * 64 + c4);
        const float4 x1 = *(const float4*)(base + (size_t)(r +  4 + ro) * 64 + c4);
        const float4 x2 = *(const float4*)(base + (size_t)(r +  8 + ro) * 64 + c4);
        const float4 x3 = *(const float4*)(base + (size_t)(r + 12 + ro) * 64 + c4);
        const float e0 = evec[r +  0 + ro];
        const float e1 = evec[r +  4 + ro];
        const float e2 = evec[r +  8 + ro];
        const float e3 = evec[r + 12 + ro];
        ax += e0 * x0.x + e1 * x1.x + e2 * x2.x + e3 * x3.x;
        ay += e0 * x0.y + e1 * x1.y + e2 * x2.y + e3 * x3.y;
        az += e0 * x0.z + e1 * x1.z + e2 * x2.z + e3 * x3.z;
        aw += e0 * x0.w + e1 * x1.w + e2 * x2.w + e3 * x3.w;
        ds += e0 + e1 + e2 + e3;
    }
    for (; r < rend; r += 4) {
        const int rr = r + ro;
        if (rr < rend) {
            const float  e = evec[rr];
            const float4 x = *(const float4*)(base + (size_t)rr * 64 + c4);
            ax += e * x.x; ay += e * x.y; az += e * x.z; aw += e * x.w;
            ds += e;
        }
    }

    // fold the 4 ro-groups (lanes differing in bits 4,5 hold same dims)
    ax += __shfl_xor(ax, 16, 64); ax += __shfl_xor(ax, 32, 64);
    ay += __shfl_xor(ay, 16, 64); ay += __shfl_xor(ay, 32, 64);
    az += __shfl_xor(az, 16, 64); az += __shfl_xor(az, 32, 64);
    aw += __shfl_xor(aw, 16, 64); aw += __shfl_xor(aw, 32, 64);
    ds += __shfl_xor(ds, 16, 64); ds += __shfl_xor(ds, 32, 64);

    __shared__ float4 part[3][16];
    __shared__ float dpart;
    if (team == 1 && lane < 16) part[arr][lane] = make_float4(ax, ay, az, aw);
    if (wave == 1 && lane == 0) dpart = ds;
    __syncthreads();

    if (team == 0 && lane < 16) {
        const float4 pp = part[arr][lane];
        const float dt = ds + dpart;     // ds identical across arrs
        const float sx = ax + pp.x, sy = ay + pp.y, sz = az + pp.z, sw = aw + pp.w;
        if (SPLIT == 1) {
            const float inv = 1.0f / dt;
            float4 o = make_float4(sx * inv, sy * inv, sz * inv, sw * inv);
            *(float4*)(dst + (size_t)s * 192 + arr * 64 + c4) = o;
        } else {
            float* P = dst + (size_t)blockIdx.x * 193;   // partials, scalar stores
            P[arr * 64 + c4 + 0] = sx;
            P[arr * 64 + c4 + 1] = sy;
            P[arr * 64 + c4 + 2] = sz;
            P[arr * 64 + c4 + 3] = sw;
            if (wave == 0 && lane == 0) P[192] = dt;
        }
    }
}

template <int SPLIT>
__global__ void finalize_kernel(const float* __restrict__ partials,
                                float* __restrict__ out) {
    const int s = blockIdx.x;
    const int d = threadIdx.x;           // 0..191
    float num = 0.f, den = 0.f;
#pragma unroll
    for (int qq = 0; qq < SPLIT; ++qq) {
        const float* P = partials + (size_t)(s * SPLIT + qq) * 193;
        num += P[d];
        den += P[192];
    }
    out[(size_t)s * 192 + d] = num / den;
}

extern "C" void kernel_launch(void* const* d_in, const int* in_sizes, int n_in,
                              void* d_out, int out_size, void* d_ws, size_t ws_size,
                              hipStream_t stream) {
    const float* ht   = (const float*)d_in[0];
    const float* info = (const float*)d_in[1];
    const float* fut  = (const float*)d_in[2];
    const int*   seg  = (const int*)d_in[3];
    const float* w1   = (const float*)d_in[4];
    const float* b1   = (const float*)d_in[5];
    const float* w2   = (const float*)d_in[6];
    const float* b2   = (const float*)d_in[7];

    float* out = (float*)d_out;

    // workspace: [starts 1025 ints][pad][evec 400000 f][partials 2048*193 f]
    int*   starts   = (int*)d_ws;
    float* evec     = (float*)d_ws + 1088;            // byte offset 4352
    float* partials = evec + MROWS;
    const size_t need_split2 = (size_t)(1088 + MROWS + NOBS * 2 * 193) * 4;

    bounds_kernel<<<(MROWS + 255) / 256, 256, 0, stream>>>(seg, starts);
    score_kernel<<<2048, 256, 0, stream>>>(ht, info, w1, b1, w2, b2, evec);

    if (ws_size >= need_split2) {
        pool_kernel<2><<<NOBS * 2, 384, 0, stream>>>(ht, info, fut, starts, evec, partials);
        finalize_kernel<2><<<NOBS, 192, 0, stream>>>(partials, out);
    } else {
        pool_kernel<1><<<NOBS, 384, 0, stream>>>(ht, info, fut, starts, evec, out);
    }
}

// Round 7
// 325.638 us; speedup vs baseline: 1.1967x; 1.0746x over previous
//
#include <hip/hip_runtime.h>

#define MROWS 400000
#define NOBS 1024
#define NTILES 6250   // MROWS / 64 exactly

// ---------------------------------------------------------------------------
// R6/R7: fix score_kernel's real bottleneck. R5 evidence: score 114us @
// 913GB/s, VALU 46%, occ 37% -> neither pipe limits; the inner loop mixed
// ds_read (x) with per-iteration s_load (weights). LDS and SMEM share
// lgkmcnt and complete out-of-order w.r.t. each other -> compiler emits
// conservative lgkmcnt(0) drains in the 32-deep loop -> serial latency
// chain (this also poisoned every fused variant R1-R4).
// Score structure: k-distributed lanes. lane=(kq=lane>>4, c=lane&15).
// Lane holds w1[32kq..32kq+31][c] in 32 VGPRs, loaded ONCE + b1[c], w2[c].
// Steady state has ZERO weight loads, zero SMEM in loop. Per row:
//   8 ds_read_b128 of the row's k-quarter (16-lane broadcast, 4 distinct
//   addrs; quarter-swizzle scol(k)=k+4*(k>>5) puts the 4 quarters on
//   disjoint bank-quads -> conflict-free), 32 FMA partial h(c),
//   shfl_xor(16,32) fold kq, relu*w2c, shfl_xor(1,2,4,8) fold c, __expf.
// Each wave owns 16 rows end-to-end: no spart barrier, no 1-wave exp phase;
// 2 barriers/tile (stage guard). 64 lanes x 32 FMA = 2048 = 128x16 exact,
// zero redundancy. VALU floor ~18us, mem floor ~33us -> memory-bound.
// Pool/bounds/finalize: unchanged from R5 (pool is near-roofline).
// (R6 submission hit a container-acquisition infra failure; identical
// source resubmitted.)
// ---------------------------------------------------------------------------

__global__ void bounds_kernel(const int* __restrict__ seg, int* __restrict__ starts) {
    const int i = blockIdx.x * 256 + threadIdx.x;
    if (i >= MROWS) return;
    const int a = seg[i];
    if (i == 0) {
        for (int j = 0; j <= a; ++j) starts[j] = 0;
    } else {
        const int b = seg[i - 1];
        for (int j = b + 1; j <= a; ++j) starts[j] = i;   // usually 0-1 iters
    }
    if (i == MROWS - 1) {
        for (int j = a + 1; j <= NOBS; ++j) starts[j] = MROWS;
    }
}

// ---- Kernel A: k-distributed scoring MLP -> evec[row] = exp(score) -------
__global__ __launch_bounds__(256, 4) void score_kernel(
    const float* __restrict__ ht, const float* __restrict__ info,
    const float* __restrict__ w1, const float* __restrict__ b1,
    const float* __restrict__ w2, const float* __restrict__ b2,
    float* __restrict__ evec) {
    const int t    = threadIdx.x;
    const int lane = t & 63;
    const int p    = t >> 6;          // wave 0..3 -> rows 16p..16p+15
    const int kq   = lane >> 4;       // k-quarter 0..3
    const int c    = lane & 15;       // hidden unit 0..15

    // X tile: 64 rows x 144 floats. col k of concat(ht,info) stored at
    // scol(k) = k + 4*(k>>5)  (quarters at 0,36,72,108 -> banks 0,4,8,12).
    __shared__ float Xl[64 * 144];

    // one-time weight preload: wv_j holds w1[32kq+4j .. +3][c]
    const float* wb = w1 + (kq * 32) * 16 + c;
    float4 wv0, wv1, wv2, wv3, wv4, wv5, wv6, wv7;
    wv0 = make_float4(wb[  0], wb[ 16], wb[ 32], wb[ 48]);
    wv1 = make_float4(wb[ 64], wb[ 80], wb[ 96], wb[112]);
    wv2 = make_float4(wb[128], wb[144], wb[160], wb[176]);
    wv3 = make_float4(wb[192], wb[208], wb[224], wb[240]);
    wv4 = make_float4(wb[256], wb[272], wb[288], wb[304]);
    wv5 = make_float4(wb[320], wb[336], wb[352], wb[368]);
    wv6 = make_float4(wb[384], wb[400], wb[416], wb[432]);
    wv7 = make_float4(wb[448], wb[464], wb[480], wb[496]);
    const float b1c = b1[c];
    const float w2c = w2[c];
    const float bb2 = b2[0];

    // staging map: thread t loads rows {r_t, +16, +32, +48}, float4 col c4o/4
    const int r_t = t >> 4;           // 0..15
    const int c4o = (t & 15) * 4;     // 0..60
    const int sA  = c4o + 4 * (c4o >> 5);        // ht   target scol
    const int sB  = 72 + c4o + 4 * (c4o >> 5);   // info target scol (k=64+c4o)

    float4 ra0, ra1, ra2, ra3, rb0, rb1, rb2, rb3;   // named, short-lived

    for (int tile = blockIdx.x; tile < NTILES; tile += gridDim.x) {
        const size_t rbase = (size_t)tile * 64;

        {   // coalesced global loads (issued before the barrier -> overlap)
            const size_t g0 = (rbase + r_t) * 64 + c4o;
            ra0 = *(const float4*)(ht + g0);
            ra1 = *(const float4*)(ht + g0 + 1024);
            ra2 = *(const float4*)(ht + g0 + 2048);
            ra3 = *(const float4*)(ht + g0 + 3072);
            rb0 = *(const float4*)(info + g0);
            rb1 = *(const float4*)(info + g0 + 1024);
            rb2 = *(const float4*)(info + g0 + 2048);
            rb3 = *(const float4*)(info + g0 + 3072);
        }
        __syncthreads();              // prev tile's LDS reads complete
        *(float4*)(Xl + (r_t     ) * 144 + sA) = ra0;
        *(float4*)(Xl + (r_t + 16) * 144 + sA) = ra1;
        *(float4*)(Xl + (r_t + 32) * 144 + sA) = ra2;
        *(float4*)(Xl + (r_t + 48) * 144 + sA) = ra3;
        *(float4*)(Xl + (r_t     ) * 144 + sB) = rb0;
        *(float4*)(Xl + (r_t + 16) * 144 + sB) = rb1;
        *(float4*)(Xl + (r_t + 32) * 144 + sB) = rb2;
        *(float4*)(Xl + (r_t + 48) * 144 + sB) = rb3;
        __syncthreads();

        float save = 0.f;
#pragma unroll 2
        for (int rr = 0; rr < 16; ++rr) {
            const float* xp = Xl + (p * 16 + rr) * 144 + kq * 36;
            const float4 x0 = *(const float4*)(xp);
            const float4 x1 = *(const float4*)(xp + 4);
            const float4 x2 = *(const float4*)(xp + 8);
            const float4 x3 = *(const float4*)(xp + 12);
            const float4 x4 = *(const float4*)(xp + 16);
            const float4 x5 = *(const float4*)(xp + 20);
            const float4 x6 = *(const float4*)(xp + 24);
            const float4 x7 = *(const float4*)(xp + 28);

            float s0 = x0.x * wv0.x + x0.y * wv0.y + x0.z * wv0.z + x0.w * wv0.w;
            float s1 = x1.x * wv1.x + x1.y * wv1.y + x1.z * wv1.z + x1.w * wv1.w;
            float s2 = x2.x * wv2.x + x2.y * wv2.y + x2.z * wv2.z + x2.w * wv2.w;
            float s3 = x3.x * wv3.x + x3.y * wv3.y + x3.z * wv3.z + x3.w * wv3.w;
            s0 += x4.x * wv4.x + x4.y * wv4.y + x4.z * wv4.z + x4.w * wv4.w;
            s1 += x5.x * wv5.x + x5.y * wv5.y + x5.z * wv5.z + x5.w * wv5.w;
            s2 += x6.x * wv6.x + x6.y * wv6.y + x6.z * wv6.z + x6.w * wv6.w;
            s3 += x7.x * wv7.x + x7.y * wv7.y + x7.z * wv7.z + x7.w * wv7.w;
            float h = (s0 + s1) + (s2 + s3);

            // fold k-quarters (lane bits 4,5)
            h += __shfl_xor(h, 16, 64);
            h += __shfl_xor(h, 32, 64);
            // per-unit relu * w2
            float tv = fmaxf(h + b1c, 0.f) * w2c;
            // fold units (lane bits 0..3)
            tv += __shfl_xor(tv, 1, 64);
            tv += __shfl_xor(tv, 2, 64);
            tv += __shfl_xor(tv, 4, 64);
            tv += __shfl_xor(tv, 8, 64);

            const float e = __expf(tv + bb2);
            save = (lane == rr) ? e : save;
        }
        if (lane < 16) evec[rbase + p * 16 + lane] = save;   // 64B/wave, contiguous
    }
}

// ---- Kernel B: streaming weighted pool (R5, unchanged) -------------------
template <int SPLIT>
__global__ __launch_bounds__(384) void pool_kernel(
    const float* __restrict__ ht, const float* __restrict__ info,
    const float* __restrict__ fut, const int* __restrict__ starts,
    const float* __restrict__ evec, float* __restrict__ dst) {
    const int s = blockIdx.x / SPLIT;
    const int q = blockIdx.x % SPLIT;
    const int start = starts[s];
    const int end   = starts[s + 1];

    const int len   = end - start;
    const int chunk = (len + SPLIT - 1) / SPLIT;
    int rbeg0 = start + q * chunk;
    int rend0 = rbeg0 + chunk;
    if (rbeg0 > end) rbeg0 = end;
    if (rend0 > end) rend0 = end;

    const int t    = threadIdx.x;
    const int wave = t >> 6;           // 0..5
    const int lane = t & 63;
    const int arr  = wave >> 1;        // 0,1,2 -> ht, info, fut
    const int team = wave & 1;
    const float* base = (arr == 0) ? ht : (arr == 1) ? info : fut;
    const int ro = lane >> 4;          // 0..3
    const int c4 = (lane & 15) * 4;

    const int midr = (rbeg0 + rend0) >> 1;
    const int rbeg = team ? midr : rbeg0;
    const int rend = team ? rend0 : midr;

    float ax = 0.f, ay = 0.f, az = 0.f, aw = 0.f, ds = 0.f;
    int r = rbeg;
    for (; r + 16 <= rend; r += 16) {
        const float4 x0 = *(const float4*)(base + (size_t)(r +  0 + ro) * 64 + c4);
        const float4 x1 = *(const float4*)(base + (size_t)(r +  4 + ro) * 64 + c4);
        const float4 x2 = *(const float4*)(base + (size_t)(r +  8 + ro) * 64 + c4);
        const float4 x3 = *(const float4*)(base + (size_t)(r + 12 + ro) * 64 + c4);
        const float e0 = evec[r +  0 + ro];
        const float e1 = evec[r +  4 + ro];
        const float e2 = evec[r +  8 + ro];
        const float e3 = evec[r + 12 + ro];
        ax += e0 * x0.x + e1 * x1.x + e2 * x2.x + e3 * x3.x;
        ay += e0 * x0.y + e1 * x1.y + e2 * x2.y + e3 * x3.y;
        az += e0 * x0.z + e1 * x1.z + e2 * x2.z + e3 * x3.z;
        aw += e0 * x0.w + e1 * x1.w + e2 * x2.w + e3 * x3.w;
        ds += e0 + e1 + e2 + e3;
    }
    for (; r < rend; r += 4) {
        const int rr = r + ro;
        if (rr < rend) {
            const float  e = evec[rr];
            const float4 x = *(const float4*)(base + (size_t)rr * 64 + c4);
            ax += e * x.x; ay += e * x.y; az += e * x.z; aw += e * x.w;
            ds += e;
        }
    }

    ax += __shfl_xor(ax, 16, 64); ax += __shfl_xor(ax, 32, 64);
    ay += __shfl_xor(ay, 16, 64); ay += __shfl_xor(ay, 32, 64);
    az += __shfl_xor(az, 16, 64); az += __shfl_xor(az, 32, 64);
    aw += __shfl_xor(aw, 16, 64); aw += __shfl_xor(aw, 32, 64);
    ds += __shfl_xor(ds, 16, 64); ds += __shfl_xor(ds, 32, 64);

    __shared__ float4 part[3][16];
    __shared__ float dpart;
    if (team == 1 && lane < 16) part[arr][lane] = make_float4(ax, ay, az, aw);
    if (wave == 1 && lane == 0) dpart = ds;
    __syncthreads();

    if (team == 0 && lane < 16) {
        const float4 pp = part[arr][lane];
        const float dt = ds + dpart;
        const float sx = ax + pp.x, sy = ay + pp.y, sz = az + pp.z, sw = aw + pp.w;
        if (SPLIT == 1) {
            const float inv = 1.0f / dt;
            float4 o = make_float4(sx * inv, sy * inv, sz * inv, sw * inv);
            *(float4*)(dst + (size_t)s * 192 + arr * 64 + c4) = o;
        } else {
            float* P = dst + (size_t)blockIdx.x * 193;
            P[arr * 64 + c4 + 0] = sx;
            P[arr * 64 + c4 + 1] = sy;
            P[arr * 64 + c4 + 2] = sz;
            P[arr * 64 + c4 + 3] = sw;
            if (wave == 0 && lane == 0) P[192] = dt;
        }
    }
}

template <int SPLIT>
__global__ void finalize_kernel(const float* __restrict__ partials,
                                float* __restrict__ out) {
    const int s = blockIdx.x;
    const int d = threadIdx.x;           // 0..191
    float num = 0.f, den = 0.f;
#pragma unroll
    for (int qq = 0; qq < SPLIT; ++qq) {
        const float* P = partials + (size_t)(s * SPLIT + qq) * 193;
        num += P[d];
        den += P[192];
    }
    out[(size_t)s * 192 + d] = num / den;
}

extern "C" void kernel_launch(void* const* d_in, const int* in_sizes, int n_in,
                              void* d_out, int out_size, void* d_ws, size_t ws_size,
                              hipStream_t stream) {
    const float* ht   = (const float*)d_in[0];
    const float* info = (const float*)d_in[1];
    const float* fut  = (const float*)d_in[2];
    const int*   seg  = (const int*)d_in[3];
    const float* w1   = (const float*)d_in[4];
    const float* b1   = (const float*)d_in[5];
    const float* w2   = (const float*)d_in[6];
    const float* b2   = (const float*)d_in[7];

    float* out = (float*)d_out;

    int*   starts   = (int*)d_ws;
    float* evec     = (float*)d_ws + 1088;            // byte offset 4352
    float* partials = evec + MROWS;
    const size_t need_split2 = (size_t)(1088 + MROWS + NOBS * 2 * 193) * 4;

    bounds_kernel<<<(MROWS + 255) / 256, 256, 0, stream>>>(seg, starts);
    score_kernel<<<2048, 256, 0, stream>>>(ht, info, w1, b1, w2, b2, evec);

    if (ws_size >= need_split2) {
        pool_kernel<2><<<NOBS * 2, 384, 0, stream>>>(ht, info, fut, starts, evec, partials);
        finalize_kernel<2><<<NOBS, 192, 0, stream>>>(partials, out);
    } else {
        pool_kernel<1><<<NOBS, 384, 0, stream>>>(ht, info, fut, starts, evec, out);
    }
}